// Round 6
// baseline (395.883 us; speedup 1.0000x reference)
//
#include <hip/hip_runtime.h>
#include <math.h>

#define N_NODES 50000
#define E_EDGES 800000
#define F_IN 100
#define HID 128
#define HEADS 2
#define OUT_C 47
#define HH (HEADS*HID)   // 256
#define MPAD 50048       // N_NODES padded to 64-row tiles (50048 = 64*782)
#define SLOTS 64         // fixed CSR slots per node (P(deg>64) ~ 1e-20)
#define APAD 264         // LDS A-row stride in ushorts (256 + 8 pad -> bank spread)

typedef float floatx4 __attribute__((ext_vector_type(4)));
typedef float float2v __attribute__((ext_vector_type(2)));
typedef short short8 __attribute__((ext_vector_type(8)));

__device__ inline ushort bf16round(float v) {
    unsigned u = __float_as_uint(v);
    return (ushort)((u + 0x7FFFu + ((u >> 16) & 1u)) >> 16);
}

// async global->LDS, 16B per lane; LDS dest = wave-uniform base + lane*16
__device__ __forceinline__ void gl_lds16(const void* g, void* l) {
    __builtin_amdgcn_global_load_lds(
        (const __attribute__((address_space(1))) unsigned int*)g,
        (__attribute__((address_space(3))) unsigned int*)l, 16, 0, 0);
}

// ---- one-node GAT aggregate (both heads) by one wave, result -> LDS row ------
// R4-verified structure: lanes half/l32; 2 edges per iter via half split.
__device__ __forceinline__ void agg_node_to_lds(
    int node, int lane,
    const ushort* __restrict__ hb, const float* __restrict__ al,
    const float* __restrict__ ar, const int* __restrict__ deg,
    const ushort* __restrict__ csr16, ushort* dstRow)
{
    const int half = lane >> 5;
    const int l32  = lane & 31;
    const int headf = l32 >> 4;
    const int n = (node < N_NODES) ? deg[node] : 0;
    float2 ard = make_float2(0.f, 0.f);
    if (node < N_NODES) ard = ((const float2*)ar)[node];

    float dsum0 = 0.f, dsum1 = 0.f;
    float2v av[4];
#pragma unroll
    for (int j = 0; j < 4; j++) av[j] = (float2v)(0.f);

    int s = 0; float w0 = 0.f, w1 = 0.f;
    if (lane < n) {
        s = (int)csr16[(size_t)node * SLOTS + lane];
        float2 aa = ((const float2*)al)[s];
        float e0 = aa.x + ard.x;
        float e1 = aa.y + ard.y;
        e0 = fmaxf(e0, 0.f) + 0.2f * fminf(e0, 0.f);
        e1 = fmaxf(e1, 0.f) + 0.2f * fminf(e1, 0.f);
        w0 = __expf(e0); w1 = __expf(e1);
        dsum0 += w0; dsum1 += w1;
    }
    for (int i = 0; i < n; i += 4) {
        int e0i = i + half;
        int   se0 = __shfl(s,  e0i);
        float u00 = __shfl(w0, e0i);
        float u01 = __shfl(w1, e0i);
        float2v we0 = (float2v)(headf ? u01 : u00);
        const uint4 q0 = *(const uint4*)(hb + (size_t)se0 * 256 + l32 * 8);
        int e1i = i + 2 + half;
        int   se1 = __shfl(s,  e1i);
        float u10 = __shfl(w0, e1i);
        float u11 = __shfl(w1, e1i);
        float2v we1 = (float2v)(headf ? u11 : u10);
        const uint4 q1 = *(const uint4*)(hb + (size_t)se1 * 256 + l32 * 8);
        float2v p;
        p.x = __uint_as_float(q0.x << 16); p.y = __uint_as_float(q0.x & 0xFFFF0000u);
        av[0] += we0 * p;
        p.x = __uint_as_float(q0.y << 16); p.y = __uint_as_float(q0.y & 0xFFFF0000u);
        av[1] += we0 * p;
        p.x = __uint_as_float(q0.z << 16); p.y = __uint_as_float(q0.z & 0xFFFF0000u);
        av[2] += we0 * p;
        p.x = __uint_as_float(q0.w << 16); p.y = __uint_as_float(q0.w & 0xFFFF0000u);
        av[3] += we0 * p;
        p.x = __uint_as_float(q1.x << 16); p.y = __uint_as_float(q1.x & 0xFFFF0000u);
        av[0] += we1 * p;
        p.x = __uint_as_float(q1.y << 16); p.y = __uint_as_float(q1.y & 0xFFFF0000u);
        av[1] += we1 * p;
        p.x = __uint_as_float(q1.z << 16); p.y = __uint_as_float(q1.z & 0xFFFF0000u);
        av[2] += we1 * p;
        p.x = __uint_as_float(q1.w << 16); p.y = __uint_as_float(q1.w & 0xFFFF0000u);
        av[3] += we1 * p;
    }
#pragma unroll
    for (int j = 0; j < 4; j++) {
        av[j].x += __shfl_xor(av[j].x, 32);
        av[j].y += __shfl_xor(av[j].y, 32);
    }
#pragma unroll
    for (int off = 32; off; off >>= 1) {
        dsum0 += __shfl_xor(dsum0, off);
        dsum1 += __shfl_xor(dsum1, off);
    }
    if (half == 0) {
        const float den = headf ? dsum1 : dsum0;
        const float inv = (n > 0) ? 1.f / den : 0.f;
        ushort r[8];
#pragma unroll
        for (int j = 0; j < 4; j++) {
            r[2*j]   = bf16round(fmaxf(av[j].x * inv, 0.f));   // ReLU
            r[2*j+1] = bf16round(fmaxf(av[j].y * inv, 0.f));
        }
        *(uint4*)(dstRow + l32 * 8) = *(uint4*)r;
    }
}

// ------ bf16 MFMA GEMM body (64x128 tile), async staging (layer-0 only) -------
__device__ __forceinline__ void gemm_body(
    int bx, int by,
    const ushort* __restrict__ Ab, const ushort* __restrict__ Wb,
    const float* __restrict__ bias,
    ushort* __restrict__ Hb,
    const float* __restrict__ attl, const float* __restrict__ attr,
    float* __restrict__ al, float* __restrict__ ar,
    int M, int Kp, ushort* sA, ushort* sB)
{
    const int t = threadIdx.x;
    const int wave = t >> 6, lane = t & 63;
    const int quad = lane >> 4, l16 = lane & 15;
    const int rl = lane >> 2, seg = lane & 3;
    const int m0 = by * 64, n0 = bx * 128;

    floatx4 acc[8];
#pragma unroll
    for (int j = 0; j < 8; j++) acc[j] = (floatx4)(0.f);

    for (int k0 = 0; k0 < Kp; k0 += 32) {
        {
            size_t gro = (size_t)(m0 + wave * 16 + rl) * Kp + k0 + seg * 8;
            gl_lds16(Ab + gro, sA + (wave * 16) * 32);
        }
#pragma unroll
        for (int j = 0; j < 2; j++) {
            int br = wave * 32 + j * 16;
            size_t gro = (size_t)(n0 + br + rl) * Kp + k0 + seg * 8;
            gl_lds16(Wb + gro, sB + br * 32);
        }
        __syncthreads();

        short8 af = *(const short8*)(sA + (wave * 16 + l16) * 32 + quad * 8);
#pragma unroll
        for (int sn = 0; sn < 8; sn++) {
            int r = sn * 16 + l16;
            short8 b = *(const short8*)(sB + r * 32 + quad * 8);
            acc[sn] = __builtin_amdgcn_mfma_f32_16x16x32_bf16(af, b, acc[sn], 0, 0, 0);
        }
        __syncthreads();
    }

    float bias_r[8], att_l[8], att_r[8];
#pragma unroll
    for (int sn = 0; sn < 8; sn++) {
        int ai = n0 + sn * 16 + l16;
        bias_r[sn] = bias[ai];
        att_l[sn] = attl[ai];
        att_r[sn] = attr[ai];
    }
#pragma unroll
    for (int r = 0; r < 4; r++) {
        int gm = m0 + wave * 16 + quad * 4 + r;
        float suml = 0.f, sumr = 0.f;
#pragma unroll
        for (int sn = 0; sn < 8; sn++) {
            float v = acc[sn][r] + bias_r[sn];
            suml += v * att_l[sn];
            sumr += v * att_r[sn];
            if (gm < M) {
                int gn = n0 + sn * 16 + l16;
                Hb[(size_t)gm * 256 + gn] = bf16round(v);
            }
        }
#pragma unroll
        for (int off = 1; off < 16; off <<= 1) {
            suml += __shfl_xor(suml, off);
            sumr += __shfl_xor(sumr, off);
        }
        if (l16 == 0 && gm < M) {
            al[gm * HEADS + bx] = suml;
            ar[gm * HEADS + bx] = sumr;
        }
    }
}

__global__ __launch_bounds__(256) void gemm_l0(
    const ushort* __restrict__ xb, const ushort* __restrict__ W0b,
    const float* __restrict__ b0,
    const float* __restrict__ attl0, const float* __restrict__ attr0,
    ushort* __restrict__ hb, float* __restrict__ al, float* __restrict__ ar)
{
    __shared__ ushort sA[64 * 32], sB[128 * 32];
    gemm_body(blockIdx.x, blockIdx.y, xb, W0b, b0,
              hb, attl0, attr0, al, ar, N_NODES, 128, sA, sB);
}

// ---- FUSED: aggregate(hb) -> LDS A-tile -> GEMM vs W1 (full N=256) -----------
// Removes the xbb global round-trip. Reads hb/al/ar (layer-0), writes
// hb2/al2/ar2 (layer-1) -- separate buffers, no in-kernel RAW hazard.
__global__ __launch_bounds__(256) void fused_agg_gemm(
    const ushort* __restrict__ hb, const float* __restrict__ al,
    const float* __restrict__ ar, const int* __restrict__ deg,
    const ushort* __restrict__ csr16,
    const ushort* __restrict__ Wb,   // W1b [256][256] bf16
    const float* __restrict__ bias,
    const float* __restrict__ attl, const float* __restrict__ attr,
    ushort* __restrict__ Hb2, float* __restrict__ al2, float* __restrict__ ar2)
{
    __shared__ ushort sA[64 * APAD];  // 33.8 KB aggregated A-tile
    __shared__ ushort sB[256 * 32];   // 16 KB B slab per k-step

    const int t = threadIdx.x;
    const int wave = t >> 6, lane = t & 63;
    const int quad = lane >> 4, l16 = lane & 15;
    const int rl = lane >> 2, seg = lane & 3;
    const int m0 = blockIdx.x * 64;

    // ---- gather phase: 16 nodes per wave into LDS rows ----
    for (int j = 0; j < 16; j++) {
        int node = m0 + wave * 16 + j;
        agg_node_to_lds(node, lane, hb, al, ar, deg, csr16,
                        sA + (size_t)(wave * 16 + j) * APAD);
    }
    __syncthreads();

    // ---- GEMM phase: C[64][256] = A @ W1^T ----
    floatx4 acc[16];
#pragma unroll
    for (int j = 0; j < 16; j++) acc[j] = (floatx4)(0.f);

    for (int k0 = 0; k0 < HH; k0 += 32) {
#pragma unroll
        for (int j = 0; j < 4; j++) {
            int br = wave * 64 + j * 16;
            size_t gro = (size_t)(br + rl) * HH + k0 + seg * 8;
            gl_lds16(Wb + gro, sB + br * 32);
        }
        __syncthreads();
        short8 af = *(const short8*)(sA + (wave * 16 + l16) * APAD + k0 + quad * 8);
#pragma unroll
        for (int sn = 0; sn < 16; sn++) {
            short8 b = *(const short8*)(sB + (sn * 16 + l16) * 32 + quad * 8);
            acc[sn] = __builtin_amdgcn_mfma_f32_16x16x32_bf16(af, b, acc[sn], 0, 0, 0);
        }
        __syncthreads();
    }

    // ---- epilogue: bias + hb2 write + alpha scores for both heads ----
#pragma unroll
    for (int h = 0; h < 2; h++) {
        float bias_r[8], att_l[8], att_r[8];
#pragma unroll
        for (int sn = 0; sn < 8; sn++) {
            int ai = h * 128 + sn * 16 + l16;
            bias_r[sn] = bias[ai];
            att_l[sn] = attl[ai];
            att_r[sn] = attr[ai];
        }
#pragma unroll
        for (int r = 0; r < 4; r++) {
            int gm = m0 + wave * 16 + quad * 4 + r;
            float suml = 0.f, sumr = 0.f;
#pragma unroll
            for (int sn = 0; sn < 8; sn++) {
                float v = acc[h * 8 + sn][r] + bias_r[sn];
                suml += v * att_l[sn];
                sumr += v * att_r[sn];
                if (gm < N_NODES) {
                    int gn = h * 128 + sn * 16 + l16;
                    Hb2[(size_t)gm * 256 + gn] = bf16round(v);
                }
            }
#pragma unroll
            for (int off = 1; off < 16; off <<= 1) {
                suml += __shfl_xor(suml, off);
                sumr += __shfl_xor(sumr, off);
            }
            if (l16 == 0 && gm < N_NODES) {
                al2[gm * HEADS + h] = suml;
                ar2[gm * HEADS + h] = sumr;
            }
        }
    }
}

// ---- FUSED: aggregate(hb2) -> LDS -> post_mp (2 GEMMs) + log_softmax ---------
__global__ __launch_bounds__(256) void fused_agg_post(
    const ushort* __restrict__ hb2, const float* __restrict__ al2,
    const float* __restrict__ ar2, const int* __restrict__ deg,
    const ushort* __restrict__ csr16,
    const ushort* __restrict__ Bb,   // Wp1b [128][256] bf16
    const float* __restrict__ bp1,
    const ushort* __restrict__ W2b,  // Wp2b padded [64][128] bf16
    const float* __restrict__ bp2,
    float* __restrict__ out, int M)
{
    __shared__ ushort sA[64 * APAD];  // 33.8 KB aggregated A-tile
    __shared__ ushort sB[128 * 32];   // 8 KB Wp1 / W2 slab
    __shared__ ushort sP[64 * 136];   // 17.4 KB p bf16 (padded stride)

    const int t = threadIdx.x;
    const int wave = t >> 6, lane = t & 63;
    const int quad = lane >> 4, l16 = lane & 15;
    const int rl = lane >> 2, seg = lane & 3;
    const int m0 = blockIdx.x * 64;

    // ---- gather phase ----
    for (int j = 0; j < 16; j++) {
        int node = m0 + wave * 16 + j;
        agg_node_to_lds(node, lane, hb2, al2, ar2, deg, csr16,
                        sA + (size_t)(wave * 16 + j) * APAD);
    }
    __syncthreads();

    // ---- stage 1: p[64][128] = A @ Wp1^T + bp1 ----
    floatx4 acc[8];
#pragma unroll
    for (int j = 0; j < 8; j++) acc[j] = (floatx4)(0.f);

    for (int k0 = 0; k0 < HH; k0 += 32) {
#pragma unroll
        for (int j = 0; j < 2; j++) {
            int br = wave * 32 + j * 16;
            size_t gro = (size_t)(br + rl) * HH + k0 + seg * 8;
            gl_lds16(Bb + gro, sB + br * 32);
        }
        __syncthreads();
        short8 af = *(const short8*)(sA + (wave * 16 + l16) * APAD + k0 + quad * 8);
#pragma unroll
        for (int sn = 0; sn < 8; sn++) {
            short8 b = *(const short8*)(sB + (sn * 16 + l16) * 32 + quad * 8);
            acc[sn] = __builtin_amdgcn_mfma_f32_16x16x32_bf16(af, b, acc[sn], 0, 0, 0);
        }
        __syncthreads();
    }
    // write p to LDS (bf16)
#pragma unroll
    for (int sn = 0; sn < 8; sn++)
#pragma unroll
        for (int r = 0; r < 4; r++) {
            int row = wave * 16 + quad * 4 + r;
            int col = sn * 16 + l16;
            sP[row * 136 + col] = bf16round(acc[sn][r] + bp1[col]);
        }
    __syncthreads();

    // ---- stage 2: logits[64][47] = p @ Wp2^T + bp2 ----
    floatx4 acc2[4];
#pragma unroll
    for (int j = 0; j < 4; j++) acc2[j] = (floatx4)(0.f);

    for (int k0 = 0; k0 < HID; k0 += 32) {
        {
            int br = wave * 16;   // 64 rows total across 4 waves
            size_t gro = (size_t)(br + rl) * HID + k0 + seg * 8;
            gl_lds16(W2b + gro, sB + br * 32);
        }
        __syncthreads();
        short8 ph = *(const short8*)(sP + (wave * 16 + l16) * 136 + k0 + quad * 8);
#pragma unroll
        for (int sn = 0; sn < 4; sn++) {
            short8 b = *(const short8*)(sB + (sn * 16 + l16) * 32 + quad * 8);
            acc2[sn] = __builtin_amdgcn_mfma_f32_16x16x32_bf16(ph, b, acc2[sn], 0, 0, 0);
        }
        __syncthreads();
    }

    // ---- bias + log_softmax ----
    float b2[4];
#pragma unroll
    for (int sn = 0; sn < 4; sn++) {
        int n = sn * 16 + l16;
        b2[sn] = (n < OUT_C) ? bp2[n] : 0.f;
    }
#pragma unroll
    for (int r = 0; r < 4; r++) {
        float v[4];
        float m = -INFINITY;
#pragma unroll
        for (int sn = 0; sn < 4; sn++) {
            int n = sn * 16 + l16;
            float xv = (n < OUT_C) ? acc2[sn][r] + b2[sn] : -INFINITY;
            v[sn] = xv;
            m = fmaxf(m, xv);
        }
#pragma unroll
        for (int off = 1; off < 16; off <<= 1) m = fmaxf(m, __shfl_xor(m, off));
        float ssum = 0.f;
#pragma unroll
        for (int sn = 0; sn < 4; sn++) {
            int n = sn * 16 + l16;
            if (n < OUT_C) ssum += __expf(v[sn] - m);
        }
#pragma unroll
        for (int off = 1; off < 16; off <<= 1) ssum += __shfl_xor(ssum, off);
        float lse = m + logf(ssum);
        int gm = m0 + wave * 16 + quad * 4 + r;
        if (gm < M) {
#pragma unroll
            for (int sn = 0; sn < 4; sn++) {
                int n = sn * 16 + l16;
                if (n < OUT_C) out[(size_t)gm * OUT_C + n] = v[sn] - lse;
            }
        }
    }
}

// ------- degree count + fused fixed-slot CSR fill + all fp32->bf16 converts ----
__global__ void count_convert(const int* __restrict__ srcv, const int* __restrict__ dstv,
                              int* __restrict__ deg, ushort* __restrict__ csr16,
                              const float* __restrict__ x,  const float* __restrict__ W0,
                              const float* __restrict__ W1, const float* __restrict__ Wp1,
                              const float* __restrict__ Wp2,
                              ushort* __restrict__ xb,  ushort* __restrict__ W0b,
                              ushort* __restrict__ W1b, ushort* __restrict__ Wp1b,
                              ushort* __restrict__ Wp2b) {
    const int cx = N_NODES * 32;        // x: 50000 rows x 32 chunks (K padded 100->128)
    const int c0 = cx + 256 * 32;       // W0: 256 rows x 32 chunks
    const int c1 = c0 + (HH * HH) / 4;  // W1
    const int c2 = c1 + (HID * HH) / 4; // Wp1
    const int c3 = c2 + (64 * HID) / 4; // Wp2 (64 padded rows)
    int i = blockIdx.x * 256 + threadIdx.x;
    if (i < E_EDGES) {
        int d = dstv[i];
        int r = atomicAdd(&deg[d], 1);
        csr16[(size_t)d * SLOTS + r] = (ushort)srcv[i];
    }
    if (i >= c3) return;
    float4 v = make_float4(0.f, 0.f, 0.f, 0.f);
    ushort* H; size_t o;
    if (i < cx) {
        int row = i >> 5, kc = (i & 31) * 4;
        if (kc < F_IN) v = *(const float4*)(x + (size_t)row * F_IN + kc);
        H = xb; o = (size_t)row * 128 + kc;
    } else if (i < c0) {
        int j = i - cx;
        int row = j >> 5, kc = (j & 31) * 4;
        if (kc < F_IN) v = *(const float4*)(W0 + (size_t)row * F_IN + kc);
        H = W0b; o = (size_t)row * 128 + kc;
    } else if (i < c1) {
        int j = i - c0;
        v = *(const float4*)(W1 + (size_t)j * 4);
        H = W1b; o = (size_t)j * 4;
    } else if (i < c2) {
        int j = i - c1;
        v = *(const float4*)(Wp1 + (size_t)j * 4);
        H = Wp1b; o = (size_t)j * 4;
    } else {
        int j = i - c2;
        int row = j >> 5;                // HID/4 = 32 chunks per row
        if (row < OUT_C) v = *(const float4*)(Wp2 + (size_t)j * 4);
        H = Wp2b; o = (size_t)j * 4;
    }
    ushort4 r;
    r.x = bf16round(v.x); r.y = bf16round(v.y);
    r.z = bf16round(v.z); r.w = bf16round(v.w);
    *(ushort4*)(H + o) = r;
}

extern "C" void kernel_launch(void* const* d_in, const int* in_sizes, int n_in,
                              void* d_out, int out_size, void* d_ws, size_t ws_size,
                              hipStream_t stream) {
    const float* x     = (const float*)d_in[0];
    const int*   ei    = (const int*)d_in[1];
    const float* W0    = (const float*)d_in[2];
    const float* b0    = (const float*)d_in[3];
    const float* attl0 = (const float*)d_in[4];
    const float* attr0 = (const float*)d_in[5];
    const float* W1    = (const float*)d_in[6];
    const float* b1    = (const float*)d_in[7];
    const float* attl1 = (const float*)d_in[8];
    const float* attr1 = (const float*)d_in[9];
    const float* Wp1   = (const float*)d_in[10];
    const float* bp1   = (const float*)d_in[11];
    const float* Wp2   = (const float*)d_in[12];
    const float* bp2   = (const float*)d_in[13];
    float* out = (float*)d_out;

    const int Nn = N_NODES, Etot = E_EDGES;
    const int* srcv = ei;
    const int* dstv = ei + Etot;

    char* ws = (char*)d_ws;
    size_t off = 0;
    auto alloc = [&](size_t bytes) -> void* {
        void* p = ws + off;
        off = (off + bytes + 255) & ~(size_t)255;
        return p;
    };
    int*    deg    = (int*)alloc((size_t)Nn * sizeof(int));
    ushort* csr16  = (ushort*)alloc((size_t)Nn * SLOTS * 2);
    float*  al     = (float*)alloc((size_t)Nn * HEADS * sizeof(float));
    float*  ar     = (float*)alloc((size_t)Nn * HEADS * sizeof(float));
    float*  al2    = (float*)alloc((size_t)Nn * HEADS * sizeof(float));
    float*  ar2    = (float*)alloc((size_t)Nn * HEADS * sizeof(float));
    ushort* xb     = (ushort*)alloc((size_t)MPAD * 128 * 2);  // x bf16, K padded
    ushort* W0b    = (ushort*)alloc((size_t)HH * 128 * 2);
    ushort* W1b    = (ushort*)alloc((size_t)HH * HH * 2);
    ushort* Wp1b   = (ushort*)alloc((size_t)HID * HH * 2);
    ushort* Wp2b   = (ushort*)alloc((size_t)64 * HID * 2);    // padded rows
    ushort* hb     = (ushort*)alloc((size_t)Nn * HH * 2);     // layer-0 h (pre-relu)
    ushort* hb2    = (ushort*)alloc((size_t)Nn * HH * 2);     // layer-1 h (pre-relu)

    hipMemsetAsync(deg, 0, (size_t)Nn * sizeof(int), stream);

    // degree count + fixed-slot CSR fill + all converts (x, W0 padded; W1/Wp1/Wp2)
    {
        const int tot = N_NODES * 32 + 256 * 32 + (HH * HH) / 4 + (HID * HH) / 4 + (64 * HID) / 4;
        const int grid = (tot + 255) / 256;   // > E/256, covers edges too
        count_convert<<<grid, 256, 0, stream>>>(
            srcv, dstv, deg, csr16, x, W0, W1, Wp1, Wp2, xb, W0b, W1b, Wp1b, Wp2b);
    }

    // L0 GEMM (async bf16 path, Kp=128), 64-row tiles
    {
        dim3 g(2, MPAD / 64);
        gemm_l0<<<g, 256, 0, stream>>>(xb, W0b, b0, attl0, attr0, hb, al, ar);
    }

    // fused aggregate + layer-1 GEMM (full N=256 per block)
    fused_agg_gemm<<<MPAD / 64, 256, 0, stream>>>(
        hb, al, ar, deg, csr16, W1b, b1, attl1, attr1, hb2, al2, ar2);

    // fused aggregate + post_mp + log_softmax
    fused_agg_post<<<MPAD / 64, 256, 0, stream>>>(
        hb2, al2, ar2, deg, csr16, Wp1b, bp1, Wp2b, bp2, out, Nn);
}

// Round 7
// 288.417 us; speedup vs baseline: 1.3726x; 1.3726x over previous
//
#include <hip/hip_runtime.h>
#include <math.h>

#define N_NODES 50000
#define E_EDGES 800000
#define F_IN 100
#define HID 128
#define HEADS 2
#define OUT_C 47
#define HH (HEADS*HID)   // 256
#define MPAD 50176       // 64*784, 784 = 8*98 -> XCD-pair swizzle divisibility
#define SLOTS 64         // fixed CSR slots per node (P(deg>64) ~ 1e-20)

typedef float floatx4 __attribute__((ext_vector_type(4)));
typedef float float2v __attribute__((ext_vector_type(2)));
typedef short short8 __attribute__((ext_vector_type(8)));

__device__ inline ushort bf16round(float v) {
    unsigned u = __float_as_uint(v);
    return (ushort)((u + 0x7FFFu + ((u >> 16) & 1u)) >> 16);
}

// async global->LDS, 16B per lane; LDS dest = wave-uniform base + lane*16
__device__ __forceinline__ void gl_lds16(const void* g, void* l) {
    __builtin_amdgcn_global_load_lds(
        (const __attribute__((address_space(1))) unsigned int*)g,
        (__attribute__((address_space(3))) unsigned int*)l, 16, 0, 0);
}

// ------ bf16 MFMA GEMM body (64x128 tile), async staging ----------------------
// Caller passes bx/by from the L2-pair swizzle: (by,0) and (by,1) run on the
// SAME XCD 8 dispatches apart, so the second column-tile's A-read is an L2 hit.
__device__ __forceinline__ void gemm_body(
    int bx, int by,
    const ushort* __restrict__ Ab, const ushort* __restrict__ Wb,
    const float* __restrict__ bias,
    ushort* __restrict__ Hb,
    const float* __restrict__ attl, const float* __restrict__ attr,
    float* __restrict__ al, float* __restrict__ ar,
    int M, int Kp, ushort* sA, ushort* sB)
{
    const int t = threadIdx.x;
    const int wave = t >> 6, lane = t & 63;
    const int quad = lane >> 4, l16 = lane & 15;
    const int rl = lane >> 2, seg = lane & 3;
    const int m0 = by * 64, n0 = bx * 128;

    floatx4 acc[8];
#pragma unroll
    for (int j = 0; j < 8; j++) acc[j] = (floatx4)(0.f);

    for (int k0 = 0; k0 < Kp; k0 += 32) {
        {
            size_t gro = (size_t)(m0 + wave * 16 + rl) * Kp + k0 + seg * 8;
            gl_lds16(Ab + gro, sA + (wave * 16) * 32);
        }
#pragma unroll
        for (int j = 0; j < 2; j++) {
            int br = wave * 32 + j * 16;
            size_t gro = (size_t)(n0 + br + rl) * Kp + k0 + seg * 8;
            gl_lds16(Wb + gro, sB + br * 32);
        }
        __syncthreads();

        short8 af = *(const short8*)(sA + (wave * 16 + l16) * 32 + quad * 8);
#pragma unroll
        for (int sn = 0; sn < 8; sn++) {
            int r = sn * 16 + l16;
            short8 b = *(const short8*)(sB + r * 32 + quad * 8);
            acc[sn] = __builtin_amdgcn_mfma_f32_16x16x32_bf16(af, b, acc[sn], 0, 0, 0);
        }
        __syncthreads();
    }

    // epilogue: C/D layout col=lane&15, row=quad*4+reg; fused alpha scores
    float bias_r[8], att_l[8], att_r[8];
#pragma unroll
    for (int sn = 0; sn < 8; sn++) {
        int ai = n0 + sn * 16 + l16;
        bias_r[sn] = bias[ai];
        att_l[sn] = attl[ai];
        att_r[sn] = attr[ai];
    }
#pragma unroll
    for (int r = 0; r < 4; r++) {
        int gm = m0 + wave * 16 + quad * 4 + r;
        float suml = 0.f, sumr = 0.f;
#pragma unroll
        for (int sn = 0; sn < 8; sn++) {
            float v = acc[sn][r] + bias_r[sn];
            suml += v * att_l[sn];
            sumr += v * att_r[sn];
            if (gm < M) {
                int gn = n0 + sn * 16 + l16;
                Hb[(size_t)gm * 256 + gn] = bf16round(v);
            }
        }
#pragma unroll
        for (int off = 1; off < 16; off <<= 1) {
            suml += __shfl_xor(suml, off);
            sumr += __shfl_xor(sumr, off);
        }
        if (l16 == 0 && gm < M) {
            al[gm * HEADS + bx] = suml;
            ar[gm * HEADS + bx] = sumr;
        }
    }
}

// L2-pair swizzle: g -> (by = (g>>4)*8 + (g&7), bx = (g>>3)&1). Blocks g and
// g+8 share by, differ in bx, and land on the same XCD (round-robin % 8).
__global__ __launch_bounds__(256) void gemm_l0(
    const ushort* __restrict__ xb, const ushort* __restrict__ W0b,
    const float* __restrict__ b0,
    const float* __restrict__ attl0, const float* __restrict__ attr0,
    ushort* __restrict__ hb, float* __restrict__ al, float* __restrict__ ar)
{
    __shared__ ushort sA[64 * 32], sB[128 * 32];
    const int g = blockIdx.x;
    const int bx = (g >> 3) & 1;
    const int by = (g >> 4) * 8 + (g & 7);
    gemm_body(bx, by, xb, W0b, b0,
              hb, attl0, attr0, al, ar, N_NODES, 128, sA, sB);
}

__global__ __launch_bounds__(256) void gemm_l1(
    const ushort* __restrict__ Ab, const ushort* __restrict__ Wb,
    const float* __restrict__ bias, ushort* __restrict__ Hb,
    const float* __restrict__ attl, const float* __restrict__ attr,
    float* __restrict__ al, float* __restrict__ ar)
{
    __shared__ ushort sA[64 * 32], sB[128 * 32];
    const int g = blockIdx.x;
    const int bx = (g >> 3) & 1;
    const int by = (g >> 4) * 8 + (g & 7);
    gemm_body(bx, by, Ab, Wb, bias,
              Hb, attl, attr, al, ar, N_NODES, HH, sA, sB);
}

// ------- degree count + fused fixed-slot CSR fill + all fp32->bf16 converts ----
__global__ void count_convert(const int* __restrict__ srcv, const int* __restrict__ dstv,
                              int* __restrict__ deg, ushort* __restrict__ csr16,
                              const float* __restrict__ x,  const float* __restrict__ W0,
                              const float* __restrict__ W1, const float* __restrict__ Wp1,
                              const float* __restrict__ Wp2,
                              ushort* __restrict__ xb,  ushort* __restrict__ W0b,
                              ushort* __restrict__ W1b, ushort* __restrict__ Wp1b,
                              ushort* __restrict__ Wp2b) {
    const int cx = N_NODES * 32;        // x: 50000 rows x 32 chunks (K padded 100->128)
    const int c0 = cx + 256 * 32;       // W0: 256 rows x 32 chunks
    const int c1 = c0 + (HH * HH) / 4;  // W1
    const int c2 = c1 + (HID * HH) / 4; // Wp1
    const int c3 = c2 + (64 * HID) / 4; // Wp2 (64 padded rows)
    int i = blockIdx.x * 256 + threadIdx.x;
    if (i < E_EDGES) {
        int d = dstv[i];
        int r = atomicAdd(&deg[d], 1);
        csr16[(size_t)d * SLOTS + r] = (ushort)srcv[i];
    }
    if (i >= c3) return;
    float4 v = make_float4(0.f, 0.f, 0.f, 0.f);
    ushort* H; size_t o;
    if (i < cx) {
        int row = i >> 5, kc = (i & 31) * 4;
        if (kc < F_IN) v = *(const float4*)(x + (size_t)row * F_IN + kc);
        H = xb; o = (size_t)row * 128 + kc;
    } else if (i < c0) {
        int j = i - cx;
        int row = j >> 5, kc = (j & 31) * 4;
        if (kc < F_IN) v = *(const float4*)(W0 + (size_t)row * F_IN + kc);
        H = W0b; o = (size_t)row * 128 + kc;
    } else if (i < c1) {
        int j = i - c0;
        v = *(const float4*)(W1 + (size_t)j * 4);
        H = W1b; o = (size_t)j * 4;
    } else if (i < c2) {
        int j = i - c1;
        v = *(const float4*)(Wp1 + (size_t)j * 4);
        H = Wp1b; o = (size_t)j * 4;
    } else {
        int j = i - c2;
        int row = j >> 5;                // HID/4 = 32 chunks per row
        if (row < OUT_C) v = *(const float4*)(Wp2 + (size_t)j * 4);
        H = Wp2b; o = (size_t)j * 4;
    }
    ushort4 r;
    r.x = bf16round(v.x); r.y = bf16round(v.y);
    r.z = bf16round(v.z); r.w = bf16round(v.w);
    *(ushort4*)(H + o) = r;
}

// ---- GAT aggregate, head-partitioned by XCD parity (R5, CU<->L2-bound) -------
__global__ __launch_bounds__(256) void gat_aggregate(
    const ushort* __restrict__ hb, const float* __restrict__ al, const float* __restrict__ ar,
    const int* __restrict__ deg, const ushort* __restrict__ csr16,
    ushort* __restrict__ outb)
{
    const int g = blockIdx.x;
    const int xcd = g & 7;
    const int head = xcd & 1;
    const int rank = (g >> 3) * 4 + (xcd >> 1);        // [0, 12500) per head
    const int wave = threadIdx.x >> 6;
    const int node = rank * 4 + wave;                  // [0, 50000)
    const int lane = threadIdx.x & 63;
    const int grp = lane >> 4, c = lane & 15;
    if (node >= N_NODES) return;
    const int n = deg[node];                           // <= 64 (fixed-slot CSR)
    const float ard = ar[node * HEADS + head];
    const ushort* __restrict__ hbh = hb + head * HID + c * 8;

    float dsum = 0.f;
    float2v av[4];
#pragma unroll
    for (int j = 0; j < 4; j++) av[j] = (float2v)(0.f);

    int s = 0; float w = 0.f;
    if (lane < n) {
        s = (int)csr16[(size_t)node * SLOTS + lane];
        float e = al[s * HEADS + head] + ard;
        e = fmaxf(e, 0.f) + 0.2f * fminf(e, 0.f);
        w = __expf(e);
        dsum = w;
    }
    for (int i = 0; i < n; i += 8) {
        int e0 = i + grp, e1 = i + 4 + grp;
        int   s0 = __shfl(s, e0);
        float w0 = __shfl(w, e0);
        int   s1 = __shfl(s, e1);
        float w1 = __shfl(w, e1);
        uint4 q0 = make_uint4(0u, 0u, 0u, 0u);
        uint4 q1 = make_uint4(0u, 0u, 0u, 0u);
        if (e0 < n) q0 = *(const uint4*)(hbh + (size_t)s0 * 256);
        if (e1 < n) q1 = *(const uint4*)(hbh + (size_t)s1 * 256);
        float2v we0 = (float2v)(w0);
        float2v we1 = (float2v)(w1);
        float2v p;
        p.x = __uint_as_float(q0.x << 16); p.y = __uint_as_float(q0.x & 0xFFFF0000u);
        av[0] += we0 * p;
        p.x = __uint_as_float(q0.y << 16); p.y = __uint_as_float(q0.y & 0xFFFF0000u);
        av[1] += we0 * p;
        p.x = __uint_as_float(q0.z << 16); p.y = __uint_as_float(q0.z & 0xFFFF0000u);
        av[2] += we0 * p;
        p.x = __uint_as_float(q0.w << 16); p.y = __uint_as_float(q0.w & 0xFFFF0000u);
        av[3] += we0 * p;
        p.x = __uint_as_float(q1.x << 16); p.y = __uint_as_float(q1.x & 0xFFFF0000u);
        av[0] += we1 * p;
        p.x = __uint_as_float(q1.y << 16); p.y = __uint_as_float(q1.y & 0xFFFF0000u);
        av[1] += we1 * p;
        p.x = __uint_as_float(q1.z << 16); p.y = __uint_as_float(q1.z & 0xFFFF0000u);
        av[2] += we1 * p;
        p.x = __uint_as_float(q1.w << 16); p.y = __uint_as_float(q1.w & 0xFFFF0000u);
        av[3] += we1 * p;
    }
    // reduce across the 4 edge-groups (lanes c, c+16, c+32, c+48)
#pragma unroll
    for (int j = 0; j < 4; j++) {
        av[j].x += __shfl_xor(av[j].x, 16);
        av[j].y += __shfl_xor(av[j].y, 16);
        av[j].x += __shfl_xor(av[j].x, 32);
        av[j].y += __shfl_xor(av[j].y, 32);
    }
    // full-wave denominator reduction
#pragma unroll
    for (int off = 32; off; off >>= 1) dsum += __shfl_xor(dsum, off);

    if (grp == 0) {
        const float inv = (n > 0) ? 1.f / dsum : 0.f;
        ushort r[8];
#pragma unroll
        for (int j = 0; j < 4; j++) {
            r[2*j]   = bf16round(fmaxf(av[j].x * inv, 0.f));   // ReLU
            r[2*j+1] = bf16round(fmaxf(av[j].y * inv, 0.f));
        }
        *(uint4*)(outb + (size_t)node * 256 + head * HID + c * 8) = *(uint4*)r;
    }
}

// ---------------- fused post_mp + log_softmax (64 rows/block) -----------------
// 64-row blocks: LDS 29.4KB -> ~3 co-resident blocks/CU (vs 1.5 at 128-row).
__global__ __launch_bounds__(256) void fused_post(
    const ushort* __restrict__ Ab,   // x2 [MPAD,256] bf16
    const ushort* __restrict__ Bb,   // Wp1 [128,256] bf16
    const float* __restrict__ bp1,
    const ushort* __restrict__ W2b,  // Wp2 padded [64,128] bf16
    const float* __restrict__ bp2,
    float* __restrict__ out, int M)
{
    __shared__ ushort sA[64 * 32];   // A slab / W2 tile
    __shared__ ushort sB[128 * 32];  // Wp1 slab
    __shared__ ushort sP[64 * 136];  // p bf16 (padded stride)

    const int t = threadIdx.x;
    const int wave = t >> 6, lane = t & 63;
    const int quad = lane >> 4, l16 = lane & 15;
    const int rl = lane >> 2, seg = lane & 3;
    const int m0 = blockIdx.x * 64;

    // ---- stage 1: p[64x128] = A @ Wp1^T + bp1 ----
    floatx4 acc[8];
#pragma unroll
    for (int j = 0; j < 8; j++) acc[j] = (floatx4)(0.f);

    for (int k0 = 0; k0 < HH; k0 += 32) {
        {
            size_t gro = (size_t)(m0 + wave * 16 + rl) * HH + k0 + seg * 8;
            gl_lds16(Ab + gro, sA + (wave * 16) * 32);
        }
#pragma unroll
        for (int j = 0; j < 2; j++) {
            int br = wave * 32 + j * 16;
            size_t gro = (size_t)(br + rl) * HH + k0 + seg * 8;
            gl_lds16(Bb + gro, sB + br * 32);
        }
        __syncthreads();
        short8 af = *(const short8*)(sA + (wave * 16 + l16) * 32 + quad * 8);
#pragma unroll
        for (int sn = 0; sn < 8; sn++) {
            short8 b = *(const short8*)(sB + (sn * 16 + l16) * 32 + quad * 8);
            acc[sn] = __builtin_amdgcn_mfma_f32_16x16x32_bf16(af, b, acc[sn], 0, 0, 0);
        }
        __syncthreads();
    }
    // write p to LDS (bf16)
#pragma unroll
    for (int sn = 0; sn < 8; sn++)
#pragma unroll
        for (int r = 0; r < 4; r++) {
            int row = wave * 16 + quad * 4 + r;
            int col = sn * 16 + l16;
            sP[row * 136 + col] = bf16round(acc[sn][r] + bp1[col]);
        }
    __syncthreads();

    // ---- stage 2: logits[64x47] = p @ Wp2^T + bp2 ----
    floatx4 acc2[4];
#pragma unroll
    for (int j = 0; j < 4; j++) acc2[j] = (floatx4)(0.f);

    for (int k0 = 0; k0 < HID; k0 += 32) {
        {
            int br = wave * 16;   // 64 rows total across 4 waves
            size_t gro = (size_t)(br + rl) * HID + k0 + seg * 8;
            gl_lds16(W2b + gro, sA + br * 32);
        }
        __syncthreads();
        short8 ph = *(const short8*)(sP + (wave * 16 + l16) * 136 + k0 + quad * 8);
#pragma unroll
        for (int sn = 0; sn < 4; sn++) {
            short8 b = *(const short8*)(sA + (sn * 16 + l16) * 32 + quad * 8);
            acc2[sn] = __builtin_amdgcn_mfma_f32_16x16x32_bf16(ph, b, acc2[sn], 0, 0, 0);
        }
        __syncthreads();
    }

    // ---- bias + log_softmax ----
    float b2[4];
#pragma unroll
    for (int sn = 0; sn < 4; sn++) {
        int n = sn * 16 + l16;
        b2[sn] = (n < OUT_C) ? bp2[n] : 0.f;
    }
#pragma unroll
    for (int r = 0; r < 4; r++) {
        float v[4];
        float m = -INFINITY;
#pragma unroll
        for (int sn = 0; sn < 4; sn++) {
            int n = sn * 16 + l16;
            float xv = (n < OUT_C) ? acc2[sn][r] + b2[sn] : -INFINITY;
            v[sn] = xv;
            m = fmaxf(m, xv);
        }
#pragma unroll
        for (int off = 1; off < 16; off <<= 1) m = fmaxf(m, __shfl_xor(m, off));
        float ssum = 0.f;
#pragma unroll
        for (int sn = 0; sn < 4; sn++) {
            int n = sn * 16 + l16;
            if (n < OUT_C) ssum += __expf(v[sn] - m);
        }
#pragma unroll
        for (int off = 1; off < 16; off <<= 1) ssum += __shfl_xor(ssum, off);
        float lse = m + logf(ssum);
        int gm = m0 + wave * 16 + quad * 4 + r;
        if (gm < M) {
#pragma unroll
            for (int sn = 0; sn < 4; sn++) {
                int n = sn * 16 + l16;
                if (n < OUT_C) out[(size_t)gm * OUT_C + n] = v[sn] - lse;
            }
        }
    }
}

extern "C" void kernel_launch(void* const* d_in, const int* in_sizes, int n_in,
                              void* d_out, int out_size, void* d_ws, size_t ws_size,
                              hipStream_t stream) {
    const float* x     = (const float*)d_in[0];
    const int*   ei    = (const int*)d_in[1];
    const float* W0    = (const float*)d_in[2];
    const float* b0    = (const float*)d_in[3];
    const float* attl0 = (const float*)d_in[4];
    const float* attr0 = (const float*)d_in[5];
    const float* W1    = (const float*)d_in[6];
    const float* b1    = (const float*)d_in[7];
    const float* attl1 = (const float*)d_in[8];
    const float* attr1 = (const float*)d_in[9];
    const float* Wp1   = (const float*)d_in[10];
    const float* bp1   = (const float*)d_in[11];
    const float* Wp2   = (const float*)d_in[12];
    const float* bp2   = (const float*)d_in[13];
    float* out = (float*)d_out;

    const int Nn = N_NODES, Etot = E_EDGES;
    const int* srcv = ei;
    const int* dstv = ei + Etot;

    char* ws = (char*)d_ws;
    size_t off = 0;
    auto alloc = [&](size_t bytes) -> void* {
        void* p = ws + off;
        off = (off + bytes + 255) & ~(size_t)255;
        return p;
    };
    int*    deg    = (int*)alloc((size_t)Nn * sizeof(int));
    ushort* csr16  = (ushort*)alloc((size_t)Nn * SLOTS * 2);
    float*  al     = (float*)alloc((size_t)Nn * HEADS * sizeof(float));
    float*  ar     = (float*)alloc((size_t)Nn * HEADS * sizeof(float));
    ushort* xb     = (ushort*)alloc((size_t)MPAD * 128 * 2);  // x bf16, K padded
    ushort* W0b    = (ushort*)alloc((size_t)HH * 128 * 2);
    ushort* W1b    = (ushort*)alloc((size_t)HH * HH * 2);
    ushort* Wp1b   = (ushort*)alloc((size_t)HID * HH * 2);
    ushort* Wp2b   = (ushort*)alloc((size_t)64 * HID * 2);    // padded rows
    ushort* hb     = (ushort*)alloc((size_t)MPAD * HH * 2);   // bf16 h (pre-relu)
    ushort* xbb    = (ushort*)alloc((size_t)MPAD * HH * 2);   // agg out (padded rows)

    hipMemsetAsync(deg, 0, (size_t)Nn * sizeof(int), stream);

    // degree count + fixed-slot CSR fill + all converts (x, W0 padded; W1/Wp1/Wp2)
    {
        const int tot = N_NODES * 32 + 256 * 32 + (HH * HH) / 4 + (HID * HH) / 4 + (64 * HID) / 4;
        const int grid = (tot + 255) / 256;   // > E/256, covers edges too
        count_convert<<<grid, 256, 0, stream>>>(
            srcv, dstv, deg, csr16, x, W0, W1, Wp1, Wp2, xb, W0b, W1b, Wp1b, Wp2b);
    }

    // L0 GEMM: L2-pair swizzled linear grid (2 * 784 blocks)
    gemm_l0<<<2 * (MPAD / 64), 256, 0, stream>>>(xb, W0b, b0, attl0, attr0, hb, al, ar);

    // head-partitioned aggregate: 25000 blocks = 2 heads x 12500 node-groups
    gat_aggregate<<<25000, 256, 0, stream>>>(hb, al, ar, deg, csr16, xbb);

    // Layer 1, L2-pair swizzled
    gemm_l1<<<2 * (MPAD / 64), 256, 0, stream>>>(xbb, W1b, b1, hb, attl1, attr1, al, ar);

    gat_aggregate<<<25000, 256, 0, stream>>>(hb, al, ar, deg, csr16, xbb);

    // fused post_mp + log_softmax (64-row blocks)
    fused_post<<<MPAD / 64, 256, 0, stream>>>(xbb, Wp1b, bp1, Wp2b, bp2, out, Nn);
}

// Round 8
// 287.506 us; speedup vs baseline: 1.3770x; 1.0032x over previous
//
#include <hip/hip_runtime.h>
#include <math.h>

#define N_NODES 50000
#define E_EDGES 800000
#define F_IN 100
#define HID 128
#define HEADS 2
#define OUT_C 47
#define HH (HEADS*HID)   // 256
#define MPAD 50176       // 64*784, 784 = 8*98 -> XCD-pair swizzle divisibility
#define SLOTS 64         // fixed CSR slots per node (P(deg>64) ~ 1e-20)

typedef float floatx4 __attribute__((ext_vector_type(4)));
typedef float float2v __attribute__((ext_vector_type(2)));
typedef short short8 __attribute__((ext_vector_type(8)));

__device__ inline ushort bf16round(float v) {
    unsigned u = __float_as_uint(v);
    return (ushort)((u + 0x7FFFu + ((u >> 16) & 1u)) >> 16);
}

// async global->LDS, 16B per lane; LDS dest = wave-uniform base + lane*16
__device__ __forceinline__ void gl_lds16(const void* g, void* l) {
    __builtin_amdgcn_global_load_lds(
        (const __attribute__((address_space(1))) unsigned int*)g,
        (__attribute__((address_space(3))) unsigned int*)l, 16, 0, 0);
}

// ------ bf16 MFMA GEMM body (64x128 tile), async staging ----------------------
__device__ __forceinline__ void gemm_body(
    int bx, int by,
    const ushort* __restrict__ Ab, const ushort* __restrict__ Wb,
    const float* __restrict__ bias,
    ushort* __restrict__ Hb,
    const float* __restrict__ attl, const float* __restrict__ attr,
    float* __restrict__ al, float* __restrict__ ar,
    int M, int Kp, ushort* sA, ushort* sB)
{
    const int t = threadIdx.x;
    const int wave = t >> 6, lane = t & 63;
    const int quad = lane >> 4, l16 = lane & 15;
    const int rl = lane >> 2, seg = lane & 3;
    const int m0 = by * 64, n0 = bx * 128;

    floatx4 acc[8];
#pragma unroll
    for (int j = 0; j < 8; j++) acc[j] = (floatx4)(0.f);

    for (int k0 = 0; k0 < Kp; k0 += 32) {
        {
            size_t gro = (size_t)(m0 + wave * 16 + rl) * Kp + k0 + seg * 8;
            gl_lds16(Ab + gro, sA + (wave * 16) * 32);
        }
#pragma unroll
        for (int j = 0; j < 2; j++) {
            int br = wave * 32 + j * 16;
            size_t gro = (size_t)(n0 + br + rl) * Kp + k0 + seg * 8;
            gl_lds16(Wb + gro, sB + br * 32);
        }
        __syncthreads();

        short8 af = *(const short8*)(sA + (wave * 16 + l16) * 32 + quad * 8);
#pragma unroll
        for (int sn = 0; sn < 8; sn++) {
            int r = sn * 16 + l16;
            short8 b = *(const short8*)(sB + r * 32 + quad * 8);
            acc[sn] = __builtin_amdgcn_mfma_f32_16x16x32_bf16(af, b, acc[sn], 0, 0, 0);
        }
        __syncthreads();
    }

    // epilogue: C/D layout col=lane&15, row=quad*4+reg; fused alpha scores
    float bias_r[8], att_l[8], att_r[8];
#pragma unroll
    for (int sn = 0; sn < 8; sn++) {
        int ai = n0 + sn * 16 + l16;
        bias_r[sn] = bias[ai];
        att_l[sn] = attl[ai];
        att_r[sn] = attr[ai];
    }
#pragma unroll
    for (int r = 0; r < 4; r++) {
        int gm = m0 + wave * 16 + quad * 4 + r;
        float suml = 0.f, sumr = 0.f;
#pragma unroll
        for (int sn = 0; sn < 8; sn++) {
            float v = acc[sn][r] + bias_r[sn];
            suml += v * att_l[sn];
            sumr += v * att_r[sn];
            if (gm < M) {
                int gn = n0 + sn * 16 + l16;
                Hb[(size_t)gm * 256 + gn] = bf16round(v);
            }
        }
#pragma unroll
        for (int off = 1; off < 16; off <<= 1) {
            suml += __shfl_xor(suml, off);
            sumr += __shfl_xor(sumr, off);
        }
        if (l16 == 0 && gm < M) {
            al[gm * HEADS + bx] = suml;
            ar[gm * HEADS + bx] = sumr;
        }
    }
}

// ---- prep: zero deg + ALL fp32->bf16 converts (x, W0 padded; W1/Wp1/Wp2) -----
__global__ void prep(int* __restrict__ deg,
                     const float* __restrict__ x,  const float* __restrict__ W0,
                     const float* __restrict__ W1, const float* __restrict__ Wp1,
                     const float* __restrict__ Wp2,
                     ushort* __restrict__ xb,  ushort* __restrict__ W0b,
                     ushort* __restrict__ W1b, ushort* __restrict__ Wp1b,
                     ushort* __restrict__ Wp2b) {
    const int cx = N_NODES * 32;        // x: 50000 rows x 32 chunks (K padded 100->128)
    const int c0 = cx + 256 * 32;       // W0: 256 rows x 32 chunks
    const int c1 = c0 + (HH * HH) / 4;  // W1
    const int c2 = c1 + (HID * HH) / 4; // Wp1
    const int c3 = c2 + (64 * HID) / 4; // Wp2 (64 padded rows)
    int i = blockIdx.x * 256 + threadIdx.x;
    if (i < N_NODES) deg[i] = 0;
    if (i >= c3) return;
    float4 v = make_float4(0.f, 0.f, 0.f, 0.f);
    ushort* H; size_t o;
    if (i < cx) {
        int row = i >> 5, kc = (i & 31) * 4;
        if (kc < F_IN) v = *(const float4*)(x + (size_t)row * F_IN + kc);
        H = xb; o = (size_t)row * 128 + kc;
    } else if (i < c0) {
        int j = i - cx;
        int row = j >> 5, kc = (j & 31) * 4;
        if (kc < F_IN) v = *(const float4*)(W0 + (size_t)row * F_IN + kc);
        H = W0b; o = (size_t)row * 128 + kc;
    } else if (i < c1) {
        int j = i - c0;
        v = *(const float4*)(W1 + (size_t)j * 4);
        H = W1b; o = (size_t)j * 4;
    } else if (i < c2) {
        int j = i - c1;
        v = *(const float4*)(Wp1 + (size_t)j * 4);
        H = Wp1b; o = (size_t)j * 4;
    } else {
        int j = i - c2;
        int row = j >> 5;                // HID/4 = 32 chunks per row
        if (row < OUT_C) v = *(const float4*)(Wp2 + (size_t)j * 4);
        H = Wp2b; o = (size_t)j * 4;
    }
    ushort4 r;
    r.x = bf16round(v.x); r.y = bf16round(v.y);
    r.z = bf16round(v.z); r.w = bf16round(v.w);
    *(ushort4*)(H + o) = r;
}

// ---- MERGED: L0 GEMM + edge->CSR scatter, interleaved 1:2 --------------------
// The scatter (random 2B RMW, ~25us standalone) hides behind the GEMM's MFMA
// work. Dependency-safe: csr16/deg are read only by the later aggregate.
#define NG 1568          // 2 * (MPAD/64) gemm blocks
#define NEB 3136         // edge blocks (>= 3125)
__global__ __launch_bounds__(256) void gemm_l0_edges(
    const ushort* __restrict__ xb, const ushort* __restrict__ W0b,
    const float* __restrict__ b0,
    const float* __restrict__ attl0, const float* __restrict__ attr0,
    ushort* __restrict__ hb, float* __restrict__ al, float* __restrict__ ar,
    const int* __restrict__ srcv, const int* __restrict__ dstv,
    int* __restrict__ deg, ushort* __restrict__ csr16)
{
    __shared__ ushort sA[64 * 32], sB[128 * 32];
    const int g = blockIdx.x;
    if (g % 3 == 0) {
        // gemm role: gm in [0, NG); L2-pair swizzle (gm and gm+8 same XCD: 24%8==0)
        const int gm = g / 3;
        const int bx = (gm >> 3) & 1;
        const int by = (gm >> 4) * 8 + (gm & 7);
        gemm_body(bx, by, xb, W0b, b0,
                  hb, attl0, attr0, al, ar, N_NODES, 128, sA, sB);
    } else {
        // edge role: eidx = g minus #gemm-blocks before g
        const int eidx = g - (g + 2) / 3;
        int e = eidx * 256 + threadIdx.x;
        if (e < E_EDGES) {
            int d = dstv[e];
            int r = atomicAdd(&deg[d], 1);
            if (r < SLOTS) csr16[(size_t)d * SLOTS + r] = (ushort)srcv[e];
        }
    }
}

__global__ __launch_bounds__(256) void gemm_l1(
    const ushort* __restrict__ Ab, const ushort* __restrict__ Wb,
    const float* __restrict__ bias, ushort* __restrict__ Hb,
    const float* __restrict__ attl, const float* __restrict__ attr,
    float* __restrict__ al, float* __restrict__ ar)
{
    __shared__ ushort sA[64 * 32], sB[128 * 32];
    const int g = blockIdx.x;
    const int bx = (g >> 3) & 1;
    const int by = (g >> 4) * 8 + (g & 7);
    gemm_body(bx, by, Ab, Wb, bias,
              Hb, attl, attr, al, ar, N_NODES, HH, sA, sB);
}

// ---- GAT aggregate, head-partitioned by XCD parity, guard-free inner loop ----
// Lanes >= n carry s=0,w=0: shuffled padding edges read hb row 0 (valid) and
// contribute exactly 0 -> loads need no bounds checks.
__global__ __launch_bounds__(256) void gat_aggregate(
    const ushort* __restrict__ hb, const float* __restrict__ al, const float* __restrict__ ar,
    const int* __restrict__ deg, const ushort* __restrict__ csr16,
    ushort* __restrict__ outb)
{
    const int g = blockIdx.x;
    const int xcd = g & 7;
    const int head = xcd & 1;
    const int rank = (g >> 3) * 4 + (xcd >> 1);        // [0, 12500) per head
    const int wave = threadIdx.x >> 6;
    const int node = rank * 4 + wave;                  // [0, 50000) exact
    const int lane = threadIdx.x & 63;
    const int grp = lane >> 4, c = lane & 15;
    const int n = min(deg[node], SLOTS);               // <= 64 (fixed-slot CSR)
    const float ard = ar[node * HEADS + head];
    const ushort* __restrict__ hbh = hb + head * HID + c * 8;

    float dsum = 0.f;
    float2v av[4];
#pragma unroll
    for (int j = 0; j < 4; j++) av[j] = (float2v)(0.f);

    int s = 0; float w = 0.f;
    if (lane < n) {
        s = (int)csr16[(size_t)node * SLOTS + lane];
        float e = al[s * HEADS + head] + ard;
        e = fmaxf(e, 0.f) + 0.2f * fminf(e, 0.f);
        w = __expf(e);
        dsum = w;
    }
    const int nn = (n + 7) & ~7;
    for (int i = 0; i < nn; i += 8) {
        int e0 = i + grp, e1 = i + 4 + grp;
        int   s0 = __shfl(s, e0);
        float w0 = __shfl(w, e0);
        int   s1 = __shfl(s, e1);
        float w1 = __shfl(w, e1);
        uint4 q0 = *(const uint4*)(hbh + (size_t)s0 * 256);
        uint4 q1 = *(const uint4*)(hbh + (size_t)s1 * 256);
        float2v we0 = (float2v)(w0);
        float2v we1 = (float2v)(w1);
        float2v p;
        p.x = __uint_as_float(q0.x << 16); p.y = __uint_as_float(q0.x & 0xFFFF0000u);
        av[0] += we0 * p;
        p.x = __uint_as_float(q0.y << 16); p.y = __uint_as_float(q0.y & 0xFFFF0000u);
        av[1] += we0 * p;
        p.x = __uint_as_float(q0.z << 16); p.y = __uint_as_float(q0.z & 0xFFFF0000u);
        av[2] += we0 * p;
        p.x = __uint_as_float(q0.w << 16); p.y = __uint_as_float(q0.w & 0xFFFF0000u);
        av[3] += we0 * p;
        p.x = __uint_as_float(q1.x << 16); p.y = __uint_as_float(q1.x & 0xFFFF0000u);
        av[0] += we1 * p;
        p.x = __uint_as_float(q1.y << 16); p.y = __uint_as_float(q1.y & 0xFFFF0000u);
        av[1] += we1 * p;
        p.x = __uint_as_float(q1.z << 16); p.y = __uint_as_float(q1.z & 0xFFFF0000u);
        av[2] += we1 * p;
        p.x = __uint_as_float(q1.w << 16); p.y = __uint_as_float(q1.w & 0xFFFF0000u);
        av[3] += we1 * p;
    }
    // reduce across the 4 edge-groups (lanes c, c+16, c+32, c+48)
#pragma unroll
    for (int j = 0; j < 4; j++) {
        av[j].x += __shfl_xor(av[j].x, 16);
        av[j].y += __shfl_xor(av[j].y, 16);
        av[j].x += __shfl_xor(av[j].x, 32);
        av[j].y += __shfl_xor(av[j].y, 32);
    }
    // full-wave denominator reduction
#pragma unroll
    for (int off = 32; off; off >>= 1) dsum += __shfl_xor(dsum, off);

    if (grp == 0) {
        const float inv = (n > 0) ? 1.f / dsum : 0.f;
        ushort r[8];
#pragma unroll
        for (int j = 0; j < 4; j++) {
            r[2*j]   = bf16round(fmaxf(av[j].x * inv, 0.f));   // ReLU
            r[2*j+1] = bf16round(fmaxf(av[j].y * inv, 0.f));
        }
        *(uint4*)(outb + (size_t)node * 256 + head * HID + c * 8) = *(uint4*)r;
    }
}

// ---------------- fused post_mp + log_softmax (64 rows/block) -----------------
__global__ __launch_bounds__(256) void fused_post(
    const ushort* __restrict__ Ab,   // x2 [MPAD,256] bf16
    const ushort* __restrict__ Bb,   // Wp1 [128,256] bf16
    const float* __restrict__ bp1,
    const ushort* __restrict__ W2b,  // Wp2 padded [64,128] bf16
    const float* __restrict__ bp2,
    float* __restrict__ out, int M)
{
    __shared__ ushort sA[64 * 32];   // A slab / W2 tile
    __shared__ ushort sB[128 * 32];  // Wp1 slab
    __shared__ ushort sP[64 * 136];  // p bf16 (padded stride)

    const int t = threadIdx.x;
    const int wave = t >> 6, lane = t & 63;
    const int quad = lane >> 4, l16 = lane & 15;
    const int rl = lane >> 2, seg = lane & 3;
    const int m0 = blockIdx.x * 64;

    // ---- stage 1: p[64x128] = A @ Wp1^T + bp1 ----
    floatx4 acc[8];
#pragma unroll
    for (int j = 0; j < 8; j++) acc[j] = (floatx4)(0.f);

    for (int k0 = 0; k0 < HH; k0 += 32) {
        {
            size_t gro = (size_t)(m0 + wave * 16 + rl) * HH + k0 + seg * 8;
            gl_lds16(Ab + gro, sA + (wave * 16) * 32);
        }
#pragma unroll
        for (int j = 0; j < 2; j++) {
            int br = wave * 32 + j * 16;
            size_t gro = (size_t)(br + rl) * HH + k0 + seg * 8;
            gl_lds16(Bb + gro, sB + br * 32);
        }
        __syncthreads();
        short8 af = *(const short8*)(sA + (wave * 16 + l16) * 32 + quad * 8);
#pragma unroll
        for (int sn = 0; sn < 8; sn++) {
            short8 b = *(const short8*)(sB + (sn * 16 + l16) * 32 + quad * 8);
            acc[sn] = __builtin_amdgcn_mfma_f32_16x16x32_bf16(af, b, acc[sn], 0, 0, 0);
        }
        __syncthreads();
    }
    // write p to LDS (bf16)
#pragma unroll
    for (int sn = 0; sn < 8; sn++)
#pragma unroll
        for (int r = 0; r < 4; r++) {
            int row = wave * 16 + quad * 4 + r;
            int col = sn * 16 + l16;
            sP[row * 136 + col] = bf16round(acc[sn][r] + bp1[col]);
        }
    __syncthreads();

    // ---- stage 2: logits[64x47] = p @ Wp2^T + bp2 ----
    floatx4 acc2[4];
#pragma unroll
    for (int j = 0; j < 4; j++) acc2[j] = (floatx4)(0.f);

    for (int k0 = 0; k0 < HID; k0 += 32) {
        {
            int br = wave * 16;   // 64 rows total across 4 waves
            size_t gro = (size_t)(br + rl) * HID + k0 + seg * 8;
            gl_lds16(W2b + gro, sA + br * 32);
        }
        __syncthreads();
        short8 ph = *(const short8*)(sP + (wave * 16 + l16) * 136 + k0 + quad * 8);
#pragma unroll
        for (int sn = 0; sn < 4; sn++) {
            short8 b = *(const short8*)(sA + (sn * 16 + l16) * 32 + quad * 8);
            acc2[sn] = __builtin_amdgcn_mfma_f32_16x16x32_bf16(ph, b, acc2[sn], 0, 0, 0);
        }
        __syncthreads();
    }

    // ---- bias + log_softmax ----
    float b2[4];
#pragma unroll
    for (int sn = 0; sn < 4; sn++) {
        int n = sn * 16 + l16;
        b2[sn] = (n < OUT_C) ? bp2[n] : 0.f;
    }
#pragma unroll
    for (int r = 0; r < 4; r++) {
        float v[4];
        float m = -INFINITY;
#pragma unroll
        for (int sn = 0; sn < 4; sn++) {
            int n = sn * 16 + l16;
            float xv = (n < OUT_C) ? acc2[sn][r] + b2[sn] : -INFINITY;
            v[sn] = xv;
            m = fmaxf(m, xv);
        }
#pragma unroll
        for (int off = 1; off < 16; off <<= 1) m = fmaxf(m, __shfl_xor(m, off));
        float ssum = 0.f;
#pragma unroll
        for (int sn = 0; sn < 4; sn++) {
            int n = sn * 16 + l16;
            if (n < OUT_C) ssum += __expf(v[sn] - m);
        }
#pragma unroll
        for (int off = 1; off < 16; off <<= 1) ssum += __shfl_xor(ssum, off);
        float lse = m + logf(ssum);
        int gm = m0 + wave * 16 + quad * 4 + r;
        if (gm < M) {
#pragma unroll
            for (int sn = 0; sn < 4; sn++) {
                int n = sn * 16 + l16;
                if (n < OUT_C) out[(size_t)gm * OUT_C + n] = v[sn] - lse;
            }
        }
    }
}

extern "C" void kernel_launch(void* const* d_in, const int* in_sizes, int n_in,
                              void* d_out, int out_size, void* d_ws, size_t ws_size,
                              hipStream_t stream) {
    const float* x     = (const float*)d_in[0];
    const int*   ei    = (const int*)d_in[1];
    const float* W0    = (const float*)d_in[2];
    const float* b0    = (const float*)d_in[3];
    const float* attl0 = (const float*)d_in[4];
    const float* attr0 = (const float*)d_in[5];
    const float* W1    = (const float*)d_in[6];
    const float* b1    = (const float*)d_in[7];
    const float* attl1 = (const float*)d_in[8];
    const float* attr1 = (const float*)d_in[9];
    const float* Wp1   = (const float*)d_in[10];
    const float* bp1   = (const float*)d_in[11];
    const float* Wp2   = (const float*)d_in[12];
    const float* bp2   = (const float*)d_in[13];
    float* out = (float*)d_out;

    const int Nn = N_NODES, Etot = E_EDGES;
    const int* srcv = ei;
    const int* dstv = ei + Etot;

    char* ws = (char*)d_ws;
    size_t off = 0;
    auto alloc = [&](size_t bytes) -> void* {
        void* p = ws + off;
        off = (off + bytes + 255) & ~(size_t)255;
        return p;
    };
    int*    deg    = (int*)alloc((size_t)Nn * sizeof(int));
    ushort* csr16  = (ushort*)alloc((size_t)Nn * SLOTS * 2);
    float*  al     = (float*)alloc((size_t)Nn * HEADS * sizeof(float));
    float*  ar     = (float*)alloc((size_t)Nn * HEADS * sizeof(float));
    ushort* xb     = (ushort*)alloc((size_t)MPAD * 128 * 2);  // x bf16, K padded
    ushort* W0b    = (ushort*)alloc((size_t)HH * 128 * 2);
    ushort* W1b    = (ushort*)alloc((size_t)HH * HH * 2);
    ushort* Wp1b   = (ushort*)alloc((size_t)HID * HH * 2);
    ushort* Wp2b   = (ushort*)alloc((size_t)64 * HID * 2);    // padded rows
    ushort* hb     = (ushort*)alloc((size_t)MPAD * HH * 2);   // bf16 h (pre-relu)
    ushort* xbb    = (ushort*)alloc((size_t)MPAD * HH * 2);   // agg out (padded rows)

    // prep: zero deg + all converts (1,634,816 items -> 6386 blocks)
    {
        const int tot = N_NODES * 32 + 256 * 32 + (HH * HH) / 4 + (HID * HH) / 4 + (64 * HID) / 4;
        prep<<<(tot + 255) / 256, 256, 0, stream>>>(
            deg, x, W0, W1, Wp1, Wp2, xb, W0b, W1b, Wp1b, Wp2b);
    }

    // merged L0 GEMM + edge scatter: 1568 gemm + 3136 edge blocks, 1:2 interleave
    gemm_l0_edges<<<NG + NEB, 256, 0, stream>>>(
        xb, W0b, b0, attl0, attr0, hb, al, ar, srcv, dstv, deg, csr16);

    // head-partitioned aggregate: 25000 blocks = 2 heads x 12500 node-groups
    gat_aggregate<<<25000, 256, 0, stream>>>(hb, al, ar, deg, csr16, xbb);

    // Layer 1, L2-pair swizzled
    gemm_l1<<<2 * (MPAD / 64), 256, 0, stream>>>(xbb, W1b, b1, hb, attl1, attr1, al, ar);

    gat_aggregate<<<25000, 256, 0, stream>>>(hb, al, ar, deg, csr16, xbb);

    // fused post_mp + log_softmax (64-row blocks)
    fused_post<<<MPAD / 64, 256, 0, stream>>>(xbb, Wp1b, bp1, Wp2b, bp2, out, Nn);
}

// Round 9
// 284.869 us; speedup vs baseline: 1.3897x; 1.0093x over previous
//
#include <hip/hip_runtime.h>
#include <math.h>

#define N_NODES 50000
#define E_EDGES 800000
#define F_IN 100
#define HID 128
#define HEADS 2
#define OUT_C 47
#define HH (HEADS*HID)   // 256
#define MPAD 50176       // 64*784
#define SLOTS 64         // fixed CSR slots per node (P(deg>64) ~ 1e-20)
#define NGEMM0 (MPAD/64) // 784
#define NEB 3136         // edge blocks (>= 3125)

typedef float floatx4 __attribute__((ext_vector_type(4)));
typedef float float2v __attribute__((ext_vector_type(2)));
typedef short short8 __attribute__((ext_vector_type(8)));

__device__ inline ushort bf16round(float v) {
    unsigned u = __float_as_uint(v);
    return (ushort)((u + 0x7FFFu + ((u >> 16) & 1u)) >> 16);
}

// async global->LDS, 16B per lane; LDS dest = wave-uniform base + lane*16
__device__ __forceinline__ void gl_lds16(const void* g, void* l) {
    __builtin_amdgcn_global_load_lds(
        (const __attribute__((address_space(1))) unsigned int*)g,
        (__attribute__((address_space(3))) unsigned int*)l, 16, 0, 0);
}

// ---- shared epilogue for 64x256 GEMM: bias + hb write + alpha scores (2 heads)
__device__ __forceinline__ void epi2h(
    const floatx4* acc,
    const float* __restrict__ bias,
    const float* __restrict__ attl, const float* __restrict__ attr,
    ushort* __restrict__ Hb, float* __restrict__ al, float* __restrict__ ar,
    int m0, int wave, int lane)
{
    const int quad = lane >> 4, l16 = lane & 15;
#pragma unroll
    for (int h = 0; h < 2; h++) {
        float bias_r[8], att_l[8], att_r[8];
#pragma unroll
        for (int sn = 0; sn < 8; sn++) {
            int ai = h * 128 + sn * 16 + l16;
            bias_r[sn] = bias[ai];
            att_l[sn] = attl[ai];
            att_r[sn] = attr[ai];
        }
#pragma unroll
        for (int r = 0; r < 4; r++) {
            int gm = m0 + wave * 16 + quad * 4 + r;
            float suml = 0.f, sumr = 0.f;
#pragma unroll
            for (int sn = 0; sn < 8; sn++) {
                float v = acc[h * 8 + sn][r] + bias_r[sn];
                suml += v * att_l[sn];
                sumr += v * att_r[sn];
                if (gm < N_NODES) {
                    int gn = h * 128 + sn * 16 + l16;
                    Hb[(size_t)gm * 256 + gn] = bf16round(v);
                }
            }
#pragma unroll
            for (int off = 1; off < 16; off <<= 1) {
                suml += __shfl_xor(suml, off);
                sumr += __shfl_xor(sumr, off);
            }
            if (l16 == 0 && gm < N_NODES) {
                al[gm * HEADS + h] = suml;
                ar[gm * HEADS + h] = sumr;
            }
        }
    }
}

// ---- prep: zero deg + weight fp32->bf16 converts (W0 padded, W1, Wp1, Wp2) ---
__global__ void prep(int* __restrict__ deg,
                     const float* __restrict__ W0, const float* __restrict__ W1,
                     const float* __restrict__ Wp1, const float* __restrict__ Wp2,
                     ushort* __restrict__ W0b, ushort* __restrict__ W1b,
                     ushort* __restrict__ Wp1b, ushort* __restrict__ Wp2b) {
    const int c0 = 256 * 32;            // W0: 256 rows x 32 chunks (K pad 100->128)
    const int c1 = c0 + (HH * HH) / 4;  // W1
    const int c2 = c1 + (HID * HH) / 4; // Wp1
    const int c3 = c2 + (64 * HID) / 4; // Wp2 (64 padded rows)
    int i = blockIdx.x * 256 + threadIdx.x;
    if (i < N_NODES) deg[i] = 0;
    if (i >= c3) return;
    float4 v = make_float4(0.f, 0.f, 0.f, 0.f);
    ushort* H; size_t o;
    if (i < c0) {
        int row = i >> 5, kc = (i & 31) * 4;
        if (kc < F_IN) v = *(const float4*)(W0 + (size_t)row * F_IN + kc);
        H = W0b; o = (size_t)row * 128 + kc;
    } else if (i < c1) {
        int j = i - c0;
        v = *(const float4*)(W1 + (size_t)j * 4);
        H = W1b; o = (size_t)j * 4;
    } else if (i < c2) {
        int j = i - c1;
        v = *(const float4*)(Wp1 + (size_t)j * 4);
        H = Wp1b; o = (size_t)j * 4;
    } else {
        int j = i - c2;
        int row = j >> 5;                // HID/4 = 32 chunks per row
        if (row < OUT_C) v = *(const float4*)(Wp2 + (size_t)j * 4);
        H = Wp2b; o = (size_t)j * 4;
    }
    ushort4 r;
    r.x = bf16round(v.x); r.y = bf16round(v.y);
    r.z = bf16round(v.z); r.w = bf16round(v.w);
    *(ushort4*)(H + o) = r;
}

// ---- MERGED: L0 GEMM (64x256, fp32 A on-the-fly convert) + edge scatter ------
// gemm role reads x directly (no xb buffer); 1:4 interleave with edge blocks.
__global__ __launch_bounds__(256) void gemm_l0_edges(
    const float* __restrict__ x, const ushort* __restrict__ W0b,
    const float* __restrict__ b0,
    const float* __restrict__ attl0, const float* __restrict__ attr0,
    ushort* __restrict__ hb, float* __restrict__ al, float* __restrict__ ar,
    const int* __restrict__ srcv, const int* __restrict__ dstv,
    int* __restrict__ deg, ushort* __restrict__ csr16)
{
    __shared__ ushort sA[64 * 32];
    __shared__ ushort sB[256 * 32];
    const int g = blockIdx.x;
    if (g % 5 == 0) {
        // gemm role: by in [0, 784)
        const int by = g / 5;
        const int t = threadIdx.x;
        const int wave = t >> 6, lane = t & 63;
        const int quad = lane >> 4, l16 = lane & 15;
        const int rl = lane >> 2, seg = lane & 3;
        const int m0 = by * 64;

        floatx4 acc[16];
#pragma unroll
        for (int j = 0; j < 16; j++) acc[j] = (floatx4)(0.f);

        for (int k0 = 0; k0 < 128; k0 += 32) {
            // A: x fp32 -> bf16 -> LDS (rows wave*16..+15, cols k0..k0+31)
#pragma unroll
            for (int rnd = 0; rnd < 2; rnd++) {
                int row = wave * 16 + (lane >> 3) + rnd * 8;
                int c4 = (lane & 7) * 4;
                int col = k0 + c4;
                int gmr = m0 + row;
                float4 v = make_float4(0.f, 0.f, 0.f, 0.f);
                if (gmr < N_NODES && col < F_IN)
                    v = *(const float4*)(x + (size_t)gmr * F_IN + col);
                ushort4 u;
                u.x = bf16round(v.x); u.y = bf16round(v.y);
                u.z = bf16round(v.z); u.w = bf16round(v.w);
                *(ushort4*)(sA + row * 32 + c4) = u;
            }
            // B: W0b full 256 rows x 32 cols; 4 slabs per wave
#pragma unroll
            for (int j = 0; j < 4; j++) {
                int br = wave * 64 + j * 16;
                size_t gro = (size_t)(br + rl) * 128 + k0 + seg * 8;
                gl_lds16(W0b + gro, sB + br * 32);
            }
            __syncthreads();
            short8 af = *(const short8*)(sA + (wave * 16 + l16) * 32 + quad * 8);
#pragma unroll
            for (int sn = 0; sn < 16; sn++) {
                short8 b = *(const short8*)(sB + (sn * 16 + l16) * 32 + quad * 8);
                acc[sn] = __builtin_amdgcn_mfma_f32_16x16x32_bf16(af, b, acc[sn], 0, 0, 0);
            }
            __syncthreads();
        }
        epi2h(acc, b0, attl0, attr0, hb, al, ar, m0, wave, lane);
    } else {
        // edge role: eidx in [0, 3136)
        const int eidx = g - g / 5 - 1;
        int e = eidx * 256 + threadIdx.x;
        if (e < E_EDGES) {
            int d = dstv[e];
            int r = atomicAdd(&deg[d], 1);
            if (r < SLOTS) csr16[(size_t)d * SLOTS + r] = (ushort)srcv[e];
        }
    }
}

// ---- L1 GEMM: 64x256 full-N tile, bf16 A via async staging ------------------
__global__ __launch_bounds__(256) void gemm_l1(
    const ushort* __restrict__ Ab, const ushort* __restrict__ Wb,
    const float* __restrict__ bias, ushort* __restrict__ Hb,
    const float* __restrict__ attl, const float* __restrict__ attr,
    float* __restrict__ al, float* __restrict__ ar)
{
    __shared__ ushort sA[64 * 32];
    __shared__ ushort sB[256 * 32];
    const int t = threadIdx.x;
    const int wave = t >> 6, lane = t & 63;
    const int quad = lane >> 4, l16 = lane & 15;
    const int rl = lane >> 2, seg = lane & 3;
    const int m0 = blockIdx.x * 64;

    floatx4 acc[16];
#pragma unroll
    for (int j = 0; j < 16; j++) acc[j] = (floatx4)(0.f);

    for (int k0 = 0; k0 < HH; k0 += 32) {
        {
            size_t gro = (size_t)(m0 + wave * 16 + rl) * HH + k0 + seg * 8;
            gl_lds16(Ab + gro, sA + (wave * 16) * 32);
        }
#pragma unroll
        for (int j = 0; j < 4; j++) {
            int br = wave * 64 + j * 16;
            size_t gro = (size_t)(br + rl) * HH + k0 + seg * 8;
            gl_lds16(Wb + gro, sB + br * 32);
        }
        __syncthreads();
        short8 af = *(const short8*)(sA + (wave * 16 + l16) * 32 + quad * 8);
#pragma unroll
        for (int sn = 0; sn < 16; sn++) {
            short8 b = *(const short8*)(sB + (sn * 16 + l16) * 32 + quad * 8);
            acc[sn] = __builtin_amdgcn_mfma_f32_16x16x32_bf16(af, b, acc[sn], 0, 0, 0);
        }
        __syncthreads();
    }
    epi2h(acc, bias, attl, attr, Hb, al, ar, m0, wave, lane);
}

// ---- GAT aggregate, head-partitioned by XCD parity, guard-free inner loop ----
__global__ __launch_bounds__(256) void gat_aggregate(
    const ushort* __restrict__ hb, const float* __restrict__ al, const float* __restrict__ ar,
    const int* __restrict__ deg, const ushort* __restrict__ csr16,
    ushort* __restrict__ outb)
{
    const int g = blockIdx.x;
    const int xcd = g & 7;
    const int head = xcd & 1;
    const int rank = (g >> 3) * 4 + (xcd >> 1);        // [0, 12500) per head
    const int wave = threadIdx.x >> 6;
    const int node = rank * 4 + wave;                  // [0, 50000) exact
    const int lane = threadIdx.x & 63;
    const int grp = lane >> 4, c = lane & 15;
    const int n = min(deg[node], SLOTS);               // <= 64 (fixed-slot CSR)
    const float ard = ar[node * HEADS + head];
    const ushort* __restrict__ hbh = hb + head * HID + c * 8;

    float dsum = 0.f;
    float2v av[4];
#pragma unroll
    for (int j = 0; j < 4; j++) av[j] = (float2v)(0.f);

    int s = 0; float w = 0.f;
    if (lane < n) {
        s = (int)csr16[(size_t)node * SLOTS + lane];
        float e = al[s * HEADS + head] + ard;
        e = fmaxf(e, 0.f) + 0.2f * fminf(e, 0.f);
        w = __expf(e);
        dsum = w;
    }
    const int nn = (n + 7) & ~7;
    for (int i = 0; i < nn; i += 8) {
        int e0 = i + grp, e1 = i + 4 + grp;
        int   s0 = __shfl(s, e0);
        float w0 = __shfl(w, e0);
        int   s1 = __shfl(s, e1);
        float w1 = __shfl(w, e1);
        uint4 q0 = *(const uint4*)(hbh + (size_t)s0 * 256);
        uint4 q1 = *(const uint4*)(hbh + (size_t)s1 * 256);
        float2v we0 = (float2v)(w0);
        float2v we1 = (float2v)(w1);
        float2v p;
        p.x = __uint_as_float(q0.x << 16); p.y = __uint_as_float(q0.x & 0xFFFF0000u);
        av[0] += we0 * p;
        p.x = __uint_as_float(q0.y << 16); p.y = __uint_as_float(q0.y & 0xFFFF0000u);
        av[1] += we0 * p;
        p.x = __uint_as_float(q0.z << 16); p.y = __uint_as_float(q0.z & 0xFFFF0000u);
        av[2] += we0 * p;
        p.x = __uint_as_float(q0.w << 16); p.y = __uint_as_float(q0.w & 0xFFFF0000u);
        av[3] += we0 * p;
        p.x = __uint_as_float(q1.x << 16); p.y = __uint_as_float(q1.x & 0xFFFF0000u);
        av[0] += we1 * p;
        p.x = __uint_as_float(q1.y << 16); p.y = __uint_as_float(q1.y & 0xFFFF0000u);
        av[1] += we1 * p;
        p.x = __uint_as_float(q1.z << 16); p.y = __uint_as_float(q1.z & 0xFFFF0000u);
        av[2] += we1 * p;
        p.x = __uint_as_float(q1.w << 16); p.y = __uint_as_float(q1.w & 0xFFFF0000u);
        av[3] += we1 * p;
    }
    // reduce across the 4 edge-groups (lanes c, c+16, c+32, c+48)
#pragma unroll
    for (int j = 0; j < 4; j++) {
        av[j].x += __shfl_xor(av[j].x, 16);
        av[j].y += __shfl_xor(av[j].y, 16);
        av[j].x += __shfl_xor(av[j].x, 32);
        av[j].y += __shfl_xor(av[j].y, 32);
    }
    // full-wave denominator reduction
#pragma unroll
    for (int off = 32; off; off >>= 1) dsum += __shfl_xor(dsum, off);

    if (grp == 0) {
        const float inv = (n > 0) ? 1.f / dsum : 0.f;
        ushort r[8];
#pragma unroll
        for (int j = 0; j < 4; j++) {
            r[2*j]   = bf16round(fmaxf(av[j].x * inv, 0.f));   // ReLU
            r[2*j+1] = bf16round(fmaxf(av[j].y * inv, 0.f));
        }
        *(uint4*)(outb + (size_t)node * 256 + head * HID + c * 8) = *(uint4*)r;
    }
}

// ---------------- fused post_mp + log_softmax (64 rows/block) -----------------
__global__ __launch_bounds__(256) void fused_post(
    const ushort* __restrict__ Ab,   // x2 [MPAD,256] bf16
    const ushort* __restrict__ Bb,   // Wp1 [128,256] bf16
    const float* __restrict__ bp1,
    const ushort* __restrict__ W2b,  // Wp2 padded [64,128] bf16
    const float* __restrict__ bp2,
    float* __restrict__ out, int M)
{
    __shared__ ushort sA[64 * 32];   // A slab / W2 tile
    __shared__ ushort sB[128 * 32];  // Wp1 slab
    __shared__ ushort sP[64 * 136];  // p bf16 (padded stride)

    const int t = threadIdx.x;
    const int wave = t >> 6, lane = t & 63;
    const int quad = lane >> 4, l16 = lane & 15;
    const int rl = lane >> 2, seg = lane & 3;
    const int m0 = blockIdx.x * 64;

    // ---- stage 1: p[64x128] = A @ Wp1^T + bp1 ----
    floatx4 acc[8];
#pragma unroll
    for (int j = 0; j < 8; j++) acc[j] = (floatx4)(0.f);

    for (int k0 = 0; k0 < HH; k0 += 32) {
        {
            size_t gro = (size_t)(m0 + wave * 16 + rl) * HH + k0 + seg * 8;
            gl_lds16(Ab + gro, sA + (wave * 16) * 32);
        }
#pragma unroll
        for (int j = 0; j < 2; j++) {
            int br = wave * 32 + j * 16;
            size_t gro = (size_t)(br + rl) * HH + k0 + seg * 8;
            gl_lds16(Bb + gro, sB + br * 32);
        }
        __syncthreads();
        short8 af = *(const short8*)(sA + (wave * 16 + l16) * 32 + quad * 8);
#pragma unroll
        for (int sn = 0; sn < 8; sn++) {
            short8 b = *(const short8*)(sB + (sn * 16 + l16) * 32 + quad * 8);
            acc[sn] = __builtin_amdgcn_mfma_f32_16x16x32_bf16(af, b, acc[sn], 0, 0, 0);
        }
        __syncthreads();
    }
    // write p to LDS (bf16)
#pragma unroll
    for (int sn = 0; sn < 8; sn++)
#pragma unroll
        for (int r = 0; r < 4; r++) {
            int row = wave * 16 + quad * 4 + r;
            int col = sn * 16 + l16;
            sP[row * 136 + col] = bf16round(acc[sn][r] + bp1[col]);
        }
    __syncthreads();

    // ---- stage 2: logits[64x47] = p @ Wp2^T + bp2 ----
    floatx4 acc2[4];
#pragma unroll
    for (int j = 0; j < 4; j++) acc2[j] = (floatx4)(0.f);

    for (int k0 = 0; k0 < HID; k0 += 32) {
        {
            int br = wave * 16;   // 64 rows total across 4 waves
            size_t gro = (size_t)(br + rl) * HID + k0 + seg * 8;
            gl_lds16(W2b + gro, sA + br * 32);
        }
        __syncthreads();
        short8 ph = *(const short8*)(sP + (wave * 16 + l16) * 136 + k0 + quad * 8);
#pragma unroll
        for (int sn = 0; sn < 4; sn++) {
            short8 b = *(const short8*)(sA + (sn * 16 + l16) * 32 + quad * 8);
            acc2[sn] = __builtin_amdgcn_mfma_f32_16x16x32_bf16(ph, b, acc2[sn], 0, 0, 0);
        }
        __syncthreads();
    }

    // ---- bias + log_softmax ----
    float b2[4];
#pragma unroll
    for (int sn = 0; sn < 4; sn++) {
        int n = sn * 16 + l16;
        b2[sn] = (n < OUT_C) ? bp2[n] : 0.f;
    }
#pragma unroll
    for (int r = 0; r < 4; r++) {
        float v[4];
        float m = -INFINITY;
#pragma unroll
        for (int sn = 0; sn < 4; sn++) {
            int n = sn * 16 + l16;
            float xv = (n < OUT_C) ? acc2[sn][r] + b2[sn] : -INFINITY;
            v[sn] = xv;
            m = fmaxf(m, xv);
        }
#pragma unroll
        for (int off = 1; off < 16; off <<= 1) m = fmaxf(m, __shfl_xor(m, off));
        float ssum = 0.f;
#pragma unroll
        for (int sn = 0; sn < 4; sn++) {
            int n = sn * 16 + l16;
            if (n < OUT_C) ssum += __expf(v[sn] - m);
        }
#pragma unroll
        for (int off = 1; off < 16; off <<= 1) ssum += __shfl_xor(ssum, off);
        float lse = m + logf(ssum);
        int gm = m0 + wave * 16 + quad * 4 + r;
        if (gm < M) {
#pragma unroll
            for (int sn = 0; sn < 4; sn++) {
                int n = sn * 16 + l16;
                if (n < OUT_C) out[(size_t)gm * OUT_C + n] = v[sn] - lse;
            }
        }
    }
}

extern "C" void kernel_launch(void* const* d_in, const int* in_sizes, int n_in,
                              void* d_out, int out_size, void* d_ws, size_t ws_size,
                              hipStream_t stream) {
    const float* x     = (const float*)d_in[0];
    const int*   ei    = (const int*)d_in[1];
    const float* W0    = (const float*)d_in[2];
    const float* b0    = (const float*)d_in[3];
    const float* attl0 = (const float*)d_in[4];
    const float* attr0 = (const float*)d_in[5];
    const float* W1    = (const float*)d_in[6];
    const float* b1    = (const float*)d_in[7];
    const float* attl1 = (const float*)d_in[8];
    const float* attr1 = (const float*)d_in[9];
    const float* Wp1   = (const float*)d_in[10];
    const float* bp1   = (const float*)d_in[11];
    const float* Wp2   = (const float*)d_in[12];
    const float* bp2   = (const float*)d_in[13];
    float* out = (float*)d_out;

    const int Nn = N_NODES, Etot = E_EDGES;
    const int* srcv = ei;
    const int* dstv = ei + Etot;

    char* ws = (char*)d_ws;
    size_t off = 0;
    auto alloc = [&](size_t bytes) -> void* {
        void* p = ws + off;
        off = (off + bytes + 255) & ~(size_t)255;
        return p;
    };
    int*    deg    = (int*)alloc((size_t)Nn * sizeof(int));
    ushort* csr16  = (ushort*)alloc((size_t)Nn * SLOTS * 2);
    float*  al     = (float*)alloc((size_t)Nn * HEADS * sizeof(float));
    float*  ar     = (float*)alloc((size_t)Nn * HEADS * sizeof(float));
    ushort* W0b    = (ushort*)alloc((size_t)HH * 128 * 2);
    ushort* W1b    = (ushort*)alloc((size_t)HH * HH * 2);
    ushort* Wp1b   = (ushort*)alloc((size_t)HID * HH * 2);
    ushort* Wp2b   = (ushort*)alloc((size_t)64 * HID * 2);    // padded rows
    ushort* hb     = (ushort*)alloc((size_t)MPAD * HH * 2);   // bf16 h (pre-relu)
    ushort* xbb    = (ushort*)alloc((size_t)MPAD * HH * 2);   // agg out (padded rows)

    // prep: zero deg + weight converts (196 blocks covers 50176 >= 34816 items)
    prep<<<196, 256, 0, stream>>>(deg, W0, W1, Wp1, Wp2, W0b, W1b, Wp1b, Wp2b);

    // merged L0 GEMM (64x256, direct fp32 A) + edge scatter: 784 + 3136 blocks
    gemm_l0_edges<<<NGEMM0 + NEB, 256, 0, stream>>>(
        x, W0b, b0, attl0, attr0, hb, al, ar, srcv, dstv, deg, csr16);

    // head-partitioned aggregate: 25000 blocks = 2 heads x 12500 node-groups
    gat_aggregate<<<25000, 256, 0, stream>>>(hb, al, ar, deg, csr16, xbb);

    // Layer 1: 64x256 full-N tile, 784 blocks
    gemm_l1<<<NGEMM0, 256, 0, stream>>>(xbb, W1b, b1, hb, attl1, attr1, al, ar);

    gat_aggregate<<<25000, 256, 0, stream>>>(hb, al, ar, deg, csr16, xbb);

    // fused post_mp + log_softmax (64-row blocks)
    fused_post<<<NGEMM0, 256, 0, stream>>>(xbb, Wp1b, bp1, Wp2b, bp2, out, Nn);
}